// Round 8
// baseline (154.245 us; speedup 1.0000x reference)
//
#include <hip/hip_runtime.h>
#include <hip/hip_bf16.h>
#include <math.h>

// Problem constants: B=32 V=512 K=16 D=128 E=32 NE=8192 -> BV=16384 vertices
#define NLSTR 136   // LDS row stride (ushorts) for 16x128 tiles

typedef __bf16 bf16x8 __attribute__((ext_vector_type(8)));
typedef float f32x4 __attribute__((ext_vector_type(4)));
typedef unsigned short ushort8v __attribute__((ext_vector_type(8)));

union FragU { ushort8v u; bf16x8 b; };

static __device__ inline unsigned short f2bf(float f){
  unsigned u = __float_as_uint(f);
  u += 0x7fffu + ((u >> 16) & 1u);   // RNE
  return (unsigned short)(u >> 16);
}
static __device__ inline float bf2f(unsigned short u){
  return __uint_as_float(((unsigned)u) << 16);
}
static __device__ inline unsigned pk2(float a, float b){
  union { __hip_bfloat162 h; unsigned u; } r;
  r.h = __float22bfloat162_rn(float2{a, b});
  return r.u;
}
static __device__ inline ushort8v pkcvt8(float4 a, float4 b){
  union { unsigned u[4]; ushort8v v; } r;
  r.u[0] = pk2(a.x, a.y); r.u[1] = pk2(a.z, a.w);
  r.u[2] = pk2(b.x, b.y); r.u[3] = pk2(b.z, b.w);
  return r.v;
}

// tanh-form GELU (max err ~3e-4 vs exact erf-GELU)
static __device__ inline float gelu_f(float x){
  float u = x * x;
  float p = fmaf(u, 0.07135481283f, 1.5957691216f);
  float t = x * p;
  float e = __builtin_amdgcn_exp2f(t * -1.44269504f);
  return x * __builtin_amdgcn_rcpf(1.0f + e);
}

// ---------------- prep: bf16 vertex table + fragment-order bf16 weights ----------------
// w1f: 16x16x32 B-frags, frag (kc*8+nc), elem j of lane:
//      W1[(nc*16+(lane&15))*160 + kc*32 + (lane>>4)*8 + j]
// w2f/w3f: 16x16x32 B-frags likewise (rowlen 256 / 128).
__global__ __launch_bounds__(256) void prep_kernel(
    const float* __restrict__ vf, const float* __restrict__ W1,
    const float* __restrict__ W2, const float* __restrict__ W3,
    unsigned short* __restrict__ vfbf, unsigned short* __restrict__ w1f,
    unsigned short* __restrict__ w2f, unsigned short* __restrict__ w3f)
{
  int t = blockIdx.x * 256 + threadIdx.x;
  if (t < 262144){                       // 16384*128 / 8
    const float4* src = (const float4*)vf;
    float4 x = src[t * 2], y = src[t * 2 + 1];
    *(ushort8v*)(vfbf + t * 8) = pkcvt8(x, y);
    return;
  }
  int t2 = t - 262144;
  const float* s;
  unsigned short* d;
  if (t2 < 2560){                        // w1f: 5kc x 8nc (kc*8+nc)
    int fragid = t2 >> 6, lane = t2 & 63;
    int kc = fragid >> 3, nc = fragid & 7, col = lane & 15, quad = lane >> 4;
    s = W1 + (nc * 16 + col) * 160 + kc * 32 + quad * 8;
    d = w1f + t2 * 8;
  } else if (t2 < 6656){                 // w2f: 8kc x 8nc
    int t3 = t2 - 2560;
    int fragid = t3 >> 6, lane = t3 & 63;
    int kc = fragid >> 3, nc = fragid & 7, col = lane & 15, quad = lane >> 4;
    s = W2 + (nc * 16 + col) * 256 + kc * 32 + quad * 8;
    d = w2f + t3 * 8;
  } else if (t2 < 8704){                 // w3f: 4kc x 8nc
    int t3 = t2 - 6656;
    int fragid = t3 >> 6, lane = t3 & 63;
    int kc = fragid >> 3, nc = fragid & 7, col = lane & 15, quad = lane >> 4;
    s = W3 + (nc * 16 + col) * 128 + kc * 32 + quad * 8;
    d = w3f + t3 * 8;
  } else return;
#pragma unroll
  for (int j = 0; j < 8; j++) d[j] = f2bf(s[j]);
}

// ---------------- fused ----------------
// grid 1024 x 256thr, __launch_bounds__(256,2). Block = 16 vertices.
// Stage1: BARRIER-FREE. Wave wid owns vertices wid*4..+3 independently, one per
// iteration (16x16x32, M=16 neighbors). W1 vertex-part B-frags (32) live in
// registers for the whole stage (zero B traffic); edge-part B-frags (8, 8KB)
// read from global L1 per vertex. Depth-1 per-wave pipeline: vertex it+1's
// gathers issued before vertex it's compute; no barrier -> compiler uses
// fine-grained vmcnt, edge-miss latency (~900cy) hides behind compute.
// Stage2: as before (2 barriers total).
__global__ __launch_bounds__(256, 2) void fused_kernel(
    const unsigned short* __restrict__ vfbf,
    const int* __restrict__ aadj, const int* __restrict__ badj,
    const float* __restrict__ edge, const float* __restrict__ nbs,
    const float* __restrict__ h0,
    const unsigned short* __restrict__ w1f, const unsigned short* __restrict__ w2f,
    const unsigned short* __restrict__ w3f,
    const float* __restrict__ b1, const float* __restrict__ b2, const float* __restrict__ b3,
    const float* __restrict__ lamda, const float* __restrict__ alpha,
    const int* __restrict__ lval,
    float* __restrict__ out)
{
  __shared__ __align__(16) unsigned short nl_lds[16 * NLSTR];
  __shared__ __align__(16) unsigned short sup_lds[16 * NLSTR];
  const int wid  = threadIdx.x >> 6;
  const int lane = threadIdx.x & 63;
  const int col  = lane & 15;
  const int quad = lane >> 4;
  const int v0   = blockIdx.x * 16;

  // ---- W1 vertex-part B-frags resident in registers (32 frags = 128 VGPR) ----
  FragU bw[32];
#pragma unroll
  for (int f = 0; f < 32; f++)
    bw[f].u = *(const ushort8v*)(w1f + (f * 64 + lane) * 8);

  float b1v[8];
#pragma unroll
  for (int nc = 0; nc < 8; nc++) b1v[nc] = b1[nc * 16 + col];

  // ---- preload this wave's adjacency (lane col = neighbor slot) ----
  int a_[4], e_[4];
#pragma unroll
  for (int v = 0; v < 4; v++){
    a_[v] = aadj[(v0 + wid * 4 + v) * 16 + col];
    e_[v] = badj[(v0 + wid * 4 + v) * 16 + col];
  }

  const float4* nbs4 = (const float4*)nbs;

  // double-buffered prefetch state
  ushort8v pav[2][4];
  FragU    pef[2];

  // prologue: issue + convert vertex 0
  {
    const unsigned short* r = vfbf + (size_t)a_[0] * 128 + quad * 8;
#pragma unroll
    for (int kc = 0; kc < 4; kc++) pav[0][kc] = *(const ushort8v*)(r + kc * 32);
    float4 p0 = *(const float4*)(edge + (size_t)e_[0] * 32 + quad * 8);
    float4 p1 = *(const float4*)(edge + (size_t)e_[0] * 32 + quad * 8 + 4);
    pef[0].u = pkcvt8(p0, p1);
  }

#pragma unroll
  for (int it = 0; it < 4; ++it){
    const int cur = it & 1, nxt = cur ^ 1;
    float4 pe0, pe1;
    // ---- issue vertex it+1 gathers (consumed next iteration; no barrier in between) ----
    if (it < 3){
      const unsigned short* r = vfbf + (size_t)a_[it + 1] * 128 + quad * 8;
#pragma unroll
      for (int kc = 0; kc < 4; kc++) pav[nxt][kc] = *(const ushort8v*)(r + kc * 32);
      pe0 = *(const float4*)(edge + (size_t)e_[it + 1] * 32 + quad * 8);
      pe1 = *(const float4*)(edge + (size_t)e_[it + 1] * 32 + quad * 8 + 4);
    }

    // ---- vertex it MFMA: A from prefetch regs, vertex-B from regs, edge-B from L1 ----
    f32x4 acc[8] = {};
#pragma unroll
    for (int kc = 0; kc < 4; kc++){
      FragU fa; fa.u = pav[cur][kc];
#pragma unroll
      for (int nc = 0; nc < 8; nc++)
        acc[nc] = __builtin_amdgcn_mfma_f32_16x16x32_bf16(fa.b, bw[kc * 8 + nc].b, acc[nc], 0, 0, 0);
    }
#pragma unroll
    for (int nc = 0; nc < 8; nc++){
      FragU bf_;
      bf_.u = *(const ushort8v*)(w1f + ((32 + nc) * 64 + lane) * 8);   // edge-part B (L1-hot)
      acc[nc] = __builtin_amdgcn_mfma_f32_16x16x32_bf16(pef[cur].b, bf_.b, acc[nc], 0, 0, 0);
    }

    // ---- epilogue: +b1, GELU, mask, reduce over 16 neighbors; nl -> LDS ----
    {
      const int vtx = v0 + wid * 4 + it;
      const float4 mk = nbs4[vtx * 4 + quad];
#pragma unroll
      for (int nc = 0; nc < 8; nc++){
        float g0 = gelu_f(acc[nc][0] + b1v[nc]);
        float g1 = gelu_f(acc[nc][1] + b1v[nc]);
        float g2 = gelu_f(acc[nc][2] + b1v[nc]);
        float g3 = gelu_f(acc[nc][3] + b1v[nc]);
        float s  = g0 * mk.x + g1 * mk.y + g2 * mk.z + g3 * mk.w;
        s += __shfl_xor(s, 16, 64);
        s += __shfl_xor(s, 32, 64);
        if ((nc >> 1) == quad)
          nl_lds[(wid * 4 + it) * NLSTR + nc * 16 + col] = f2bf(s);
      }
    }

    // ---- convert vertex it+1 edge (loads have had the whole epilogue to land) ----
    if (it < 3) pef[nxt].u = pkcvt8(pe0, pe1);
  }
  __syncthreads();

  // ---------------- stage 2: wave wid computes output cols [wid*32, wid*32+32) --------
  const int nc0 = 2 * wid;
  const float th = logf(lamda[0] / (float)lval[0] + 1.0f);
  const float al = alpha[0];

  f32x4 acc2[2] = {};
#pragma unroll
  for (int kc = 0; kc < 8; kc++){
    FragU a;
    if (kc < 4) a.u = *(const ushort8v*)(nl_lds + col * NLSTR + kc * 32 + quad * 8);
    else        a.u = *(const ushort8v*)(vfbf + (size_t)(v0 + col) * 128 + (kc - 4) * 32 + quad * 8);
#pragma unroll
    for (int pq = 0; pq < 2; pq++){
      FragU bf_;
      bf_.u = *(const ushort8v*)(w2f + ((kc * 8 + nc0 + pq) * 64 + lane) * 8);
      acc2[pq] = __builtin_amdgcn_mfma_f32_16x16x32_bf16(a.b, bf_.b, acc2[pq], 0, 0, 0);
    }
  }

  float sup[2][4];
#pragma unroll
  for (int pq = 0; pq < 2; pq++){
    const int d = (nc0 + pq) * 16 + col;
    const float bb = b2[d];
#pragma unroll
    for (int r = 0; r < 4; r++){
      const int vtx = v0 + quad * 4 + r;
      float hi = acc2[pq][r] + bb;
      float s = (1.f - al) * hi + al * h0[vtx * 128 + d];
      sup[pq][r] = s;
      sup_lds[(quad * 4 + r) * NLSTR + d] = f2bf(s);
    }
  }
  __syncthreads();

  f32x4 acc3[2] = {};
#pragma unroll
  for (int kc = 0; kc < 4; kc++){
    FragU a;
    a.u = *(const ushort8v*)(sup_lds + col * NLSTR + kc * 32 + quad * 8);
#pragma unroll
    for (int pq = 0; pq < 2; pq++){
      FragU bf_;
      bf_.u = *(const ushort8v*)(w3f + ((kc * 8 + nc0 + pq) * 64 + lane) * 8);
      acc3[pq] = __builtin_amdgcn_mfma_f32_16x16x32_bf16(a.b, bf_.b, acc3[pq], 0, 0, 0);
    }
  }

#pragma unroll
  for (int pq = 0; pq < 2; pq++){
    const int d = (nc0 + pq) * 16 + col;
    const float bb = b3[d];
#pragma unroll
    for (int r = 0; r < 4; r++){
      const int vtx = v0 + quad * 4 + r;
      float res = bf2f(vfbf[(size_t)vtx * 128 + d]);
      out[vtx * 128 + d] = th * (acc3[pq][r] + bb) + (1.f - th) * sup[pq][r] + res;
    }
  }
}

extern "C" void kernel_launch(void* const* d_in, const int* in_sizes, int n_in,
                              void* d_out, int out_size, void* d_ws, size_t ws_size,
                              hipStream_t stream)
{
  const float* vfp  = (const float*)d_in[0];
  const int*   aadj = (const int*)d_in[1];
  const int*   badj = (const int*)d_in[2];
  const float* h0   = (const float*)d_in[3];
  const float* lam  = (const float*)d_in[4];
  const float* alp  = (const float*)d_in[5];
  const int*   lv   = (const int*)d_in[6];
  const float* edge = (const float*)d_in[7];
  // d_in[8] vertex_mask: unused by the reference math
  const float* nbs  = (const float*)d_in[9];
  const float* W1   = (const float*)d_in[10];
  const float* b1   = (const float*)d_in[11];
  const float* W2   = (const float*)d_in[12];
  const float* b2   = (const float*)d_in[13];
  const float* W3   = (const float*)d_in[14];
  const float* b3   = (const float*)d_in[15];
  float* out = (float*)d_out;

  // ws layout (ushorts): w1f [0,20480) | w2f [20480,53248) | w3f [53248,69632)
  //                      | vfbf [69632, 69632+2097152)
  unsigned short* w1f  = (unsigned short*)d_ws;
  unsigned short* w2f  = w1f + 20480;
  unsigned short* w3f  = w2f + 32768;
  unsigned short* vfbf = w3f + 16384;

  prep_kernel<<<1058, 256, 0, stream>>>(vfp, W1, W2, W3, vfbf, w1f, w2f, w3f);
  fused_kernel<<<1024, 256, 0, stream>>>(vfbf, aadj, badj, edge, nbs, h0,
                                         w1f, w2f, w3f, b1, b2, b3, lam, alp, lv, out);
}